// Round 5
// baseline (795.106 us; speedup 1.0000x reference)
//
#include <hip/hip_runtime.h>
#include <hip/hip_bf16.h>

// MPAttentionInflationBlock on MI355X — round 5.
// vs round 4 (passed, 735us): attention restructured from 1-wave-per-(seq,head)
// latency-bound blocks (82us, 3% HBM, 26% VALU) to 1-block-per-seq with
// global_load_lds slab staging (16x1536 bf16, rows padded to 1544), 4 waves x
// 2 heads each, all compute LDS-local. GEMMs/transposes unchanged (passing).

typedef __attribute__((ext_vector_type(8))) __bf16 bf16x8;
typedef __attribute__((ext_vector_type(4))) __bf16 bf16x4;
typedef __attribute__((ext_vector_type(4))) float  f32x4;

#define MP_NEW 0.9191450300180579f   // 0.7 / sqrt(0.58)
#define MP_RES 0.3939192985791677f   // 0.3 / sqrt(0.58)

__device__ __forceinline__ __hip_bfloat16 f2b(float x) { return __float2bfloat16(x); }
__device__ __forceinline__ float b2f(__hip_bfloat16 x) { return __bfloat162float(x); }

#define GLOAD16(g, l)                                                             \
  __builtin_amdgcn_global_load_lds((const __attribute__((address_space(1))) void*)(g), \
                                   (__attribute__((address_space(3))) void*)(l), 16, 0, 0)

// -------- diagnostic fallback: ws too small -> unmistakable output --------
__global__ __launch_bounds__(256)
void fill_kernel(float* o, int n)
{
  int i = blockIdx.x * 256 + threadIdx.x;
  if (i < n) o[i] = 12345.0f;
}

// -------- weight row-l2norm: wn = w/max(||w||,1e-4)/sqrt(512), f32->bf16 --------
__global__ __launch_bounds__(64)
void wnorm_pack(const float* __restrict__ w, __hip_bfloat16* __restrict__ o)
{
  const int r = blockIdx.x, lane = threadIdx.x;
  const float* wr = w + (size_t)r * 512;
  float x[8], s = 0.f;
  #pragma unroll
  for (int e = 0; e < 8; ++e) { x[e] = wr[e * 64 + lane]; s += x[e] * x[e]; }
  #pragma unroll
  for (int m = 1; m < 64; m <<= 1) s += __shfl_xor(s, m);
  const float scale = 1.0f / (fmaxf(sqrtf(s), 1e-4f) * 22.62741699796952f); // *sqrt(512)
  #pragma unroll
  for (int e = 0; e < 8; ++e) o[(size_t)r * 512 + e * 64 + lane] = f2b(x[e] * scale);
}

// -------- x[b,c,t,h,w] (f32) -> Y0[m][c] (bf16 token-major) --------
__global__ __launch_bounds__(256)
void transpose_in(const float* __restrict__ x, __hip_bfloat16* __restrict__ Y0)
{
  __shared__ float tile[32][33];
  const int tx = threadIdx.x, ty = threadIdx.y;
  const int hh = blockIdx.x;
  const int c0 = blockIdx.y * 32;
  const int bt = blockIdx.z;
  const int b = bt >> 4, t = bt & 15;
  const float* xb = x + (size_t)b * 8388608 + (size_t)t * 1024 + hh * 32 + tx;
  #pragma unroll
  for (int r = 0; r < 4; ++r) {
    const int cc = ty * 4 + r;
    tile[tx][cc] = xb[(size_t)(c0 + cc) * 16384];   // 32 consecutive w: coalesced
  }
  __syncthreads();
  #pragma unroll
  for (int r = 0; r < 4; ++r) {
    const int w = ty * 4 + r;
    const size_t m = ((size_t)b * 1024 + hh * 32 + w) * 16 + t;
    Y0[m * 512 + c0 + tx] = f2b(tile[w][tx]);       // 32 consecutive c: coalesced
  }
}

// -------- Yf[m][c] (bf16) -> out[b,c,t,h,w] (f32) --------
__global__ __launch_bounds__(256)
void transpose_out(const __hip_bfloat16* __restrict__ Yf, float* __restrict__ out)
{
  __shared__ __align__(16) __hip_bfloat16 tile[32][33];
  const int tx = threadIdx.x, ty = threadIdx.y;
  const int hh = blockIdx.x;
  const int c0 = blockIdx.y * 32;
  const int bt = blockIdx.z;
  const int b = bt >> 4, t = bt & 15;
  #pragma unroll
  for (int r = 0; r < 4; ++r) {
    const int w = ty * 4 + r;
    const size_t m = ((size_t)b * 1024 + hh * 32 + w) * 16 + t;
    tile[w][tx] = Yf[m * 512 + c0 + tx];
  }
  __syncthreads();
  float* ob = out + (size_t)b * 8388608 + (size_t)t * 1024 + hh * 32 + tx;
  #pragma unroll
  for (int r = 0; r < 4; ++r) {
    const int cc = ty * 4 + r;
    ob[(size_t)(c0 + cc) * 16384] = b2f(tile[tx][cc]);
  }
}

// -------- attention: one block per seq (16 tokens, 8 heads), 4 waves --------
// QKV[seq]: 16 rows x 1536 bf16 staged to LDS slab (rows padded to 1544 elems;
// pad legal with linear global_load_lds because 3072B row = 3 x 1024B chunks).
// Wave w handles heads 2w, 2w+1. Normalized q -> slab (bf16); normalized K
// (incl 4 mem-K) -> per-wave f32 scratch; V in registers. Output overwrites
// the q-columns of QKVc in place (blocks touch disjoint seqs).
#define SLAB_LD 1544
__global__ __launch_bounds__(256)
void attn_kernel(__hip_bfloat16* __restrict__ QKV, const float* __restrict__ mkv)
{
  __shared__ __align__(16) __hip_bfloat16 slab[16 * SLAB_LD];  // 49,408 B
  __shared__ __align__(16) float KsS[4][20][68];               // 21,760 B
  __shared__ __align__(16) float PsS[4][320];                  //  5,120 B
  const int tid = threadIdx.x;
  const int wid = tid >> 6, lane = tid & 63;
  const int seq = blockIdx.x;
  __hip_bfloat16* gbase = QKV + (size_t)seq * 16 * 1536;

  // ---- stage 16x1536 bf16 -> slab: 48 x 1KB wave-chunks, 12 per wave ----
  #pragma unroll
  for (int u = 0; u < 12; ++u) {
    const int o = wid * 12 + u;            // chunk id 0..47
    const int r = o / 3, c = o % 3;        // row, 1KB-chunk within row
    const __hip_bfloat16* g = gbase + r * 1536 + c * 512 + lane * 8;
    GLOAD16(g, (char*)slab + r * (SLAB_LD * 2) + c * 1024 + wid * 0);
  }
  __syncthreads();   // slab ready (compiler drains vmcnt before barrier)

  float (*Ks)[68] = KsS[wid];
  float* Ps = PsS[wid];

  #pragma unroll
  for (int hh = 0; hh < 2; ++hh) {
    const int h = wid * 2 + hh;
    const int hc = h * 64 + lane;

    // ---- load q,k,v (lane = d) from slab / mem_kv ----
    float q[16], k[20], v[20];
    #pragma unroll
    for (int i = 0; i < 16; ++i) q[i] = b2f(slab[i * SLAB_LD + hc]);
    #pragma unroll
    for (int j = 0; j < 4; ++j) {
      k[j] = mkv[(h * 4 + j) * 64 + lane];          // mem_kv[l][0][h][j][d] (f32)
      v[j] = mkv[2048 + (h * 4 + j) * 64 + lane];   // mem_kv[l][1][h][j][d]
    }
    #pragma unroll
    for (int j = 0; j < 16; ++j) {
      k[4 + j] = b2f(slab[j * SLAB_LD + 512 + hc]);
      v[4 + j] = b2f(slab[j * SLAB_LD + 1024 + hc]);
    }

    // ---- pixel_norm: q net 1/max(||q||,eps); k,v: 8/max(||.||,eps) ----
    #pragma unroll
    for (int i = 0; i < 16; ++i) {
      float s = q[i] * q[i];
      #pragma unroll
      for (int m = 1; m < 64; m <<= 1) s += __shfl_xor(s, m);
      q[i] *= 1.0f / fmaxf(sqrtf(s), 1e-4f);
      slab[i * SLAB_LD + hc] = f2b(q[i]);           // normalized q back to slab
    }
    #pragma unroll
    for (int j = 0; j < 20; ++j) {
      float s = k[j] * k[j];
      #pragma unroll
      for (int m = 1; m < 64; m <<= 1) s += __shfl_xor(s, m);
      Ks[j][lane] = k[j] * (8.0f / fmaxf(sqrtf(s), 1e-4f));
      float sv = v[j] * v[j];
      #pragma unroll
      for (int m = 1; m < 64; m <<= 1) sv += __shfl_xor(sv, m);
      v[j] *= 8.0f / fmaxf(sqrtf(sv), 1e-4f);
    }
    // within-wave LDS deps: compiler inserts lgkmcnt; no barrier needed
    // (each wave reads only its own heads' columns / its own scratch)

    // ---- sim[i][j]: 320 pairs over 64 lanes -> 5 per lane ----
    #pragma unroll
    for (int pp = 0; pp < 5; ++pp) {
      const int p = lane + (pp << 6);
      const int i = p / 20;
      const int j = p - i * 20;
      float s = 0.f;
      #pragma unroll
      for (int d4 = 0; d4 < 16; ++d4) {
        bf16x4 qv = *(const bf16x4*)&slab[i * SLAB_LD + h * 64 + d4 * 4];
        float4  kv = *(const float4*)&Ks[j][d4 * 4];
        s += b2f(qv[0]) * kv.x + b2f(qv[1]) * kv.y + b2f(qv[2]) * kv.z + b2f(qv[3]) * kv.w;
      }
      Ps[i * 20 + j] = s;
    }

    // ---- row softmax (lanes 0..15) ----
    if (lane < 16) {
      float mx = -1e30f;
      #pragma unroll
      for (int j = 0; j < 20; ++j) mx = fmaxf(mx, Ps[lane * 20 + j]);
      float e[20], ssum = 0.f;
      #pragma unroll
      for (int j = 0; j < 20; ++j) { e[j] = expf(Ps[lane * 20 + j] - mx); ssum += e[j]; }
      const float inv = 1.0f / ssum;
      #pragma unroll
      for (int j = 0; j < 20; ++j) Ps[lane * 20 + j] = e[j] * inv;
    }

    // ---- out[i][d] = sum_j P[i][j]*v[j][d] -> overwrite global q-cols ----
    __hip_bfloat16* ob = gbase + hc;
    #pragma unroll
    for (int i = 0; i < 16; ++i) {
      float s = 0.f;
      #pragma unroll
      for (int j = 0; j < 20; ++j) s += Ps[i * 20 + j] * v[j];  // broadcast LDS reads
      ob[(size_t)i * 1536] = f2b(s);
    }
  }
}

// -------- bf16 gemm_bt: C[m][n] = sum_k A[m][k]*Bw[n][k], K=512, 128x128 tile --------
// T2 swizzle both-sides (rule #21); T1 XCD block swizzle.
// MODE 0: out = C                     [QKV, ldo=1536]
// MODE 1: out = MP_NEW*C + MP_RES*res [out-proj, ldo=512]
// MODE 2: out = MP_NEW*(C*gain) + MP_RES*res [final proj]
template<int MODE>
__global__ __launch_bounds__(256)
void gemm3(const __hip_bfloat16* __restrict__ A, const __hip_bfloat16* __restrict__ Bw,
           int lda, __hip_bfloat16* __restrict__ outp, int ldo,
           const __hip_bfloat16* __restrict__ res, const float* __restrict__ gainp)
{
  __shared__ __hip_bfloat16 sA[128 * 64];
  __shared__ __hip_bfloat16 sB[128 * 64];
  const int nwg = gridDim.x * gridDim.y;
  int bid = blockIdx.y * gridDim.x + blockIdx.x;
  bid = (bid & 7) * (nwg >> 3) + (bid >> 3);
  const int bn = bid % gridDim.x, bm = bid / gridDim.x;

  const int tid = threadIdx.x;
  const int wid = tid >> 6, lane = tid & 63;
  const int wrow = wid >> 1, wcol = wid & 1;
  const int fr = lane & 15, fq = lane >> 4;
  const int rowL = tid >> 3;
  const int colSwz = (((tid & 7) ^ (rowL & 7)) * 8);

  const __hip_bfloat16* Ab = A  + (size_t)bm * 128 * lda;
  const __hip_bfloat16* Bb = Bw + (size_t)bn * 128 * 512;

  f32x4 acc[4][4];
  const f32x4 zz = {0.f, 0.f, 0.f, 0.f};
  #pragma unroll
  for (int i = 0; i < 4; ++i)
    #pragma unroll
    for (int j = 0; j < 4; ++j) acc[i][j] = zz;

  for (int ks = 0; ks < 8; ++ks) {
    const int k0 = ks * 64;
    __syncthreads();
    #pragma unroll
    for (int call = 0; call < 4; ++call) {
      const __hip_bfloat16* ga = Ab + (size_t)(call * 32 + rowL) * lda + k0 + colSwz;
      GLOAD16(ga, (char*)sA + call * 4096 + wid * 1024);
    }
    #pragma unroll
    for (int call = 0; call < 4; ++call) {
      const __hip_bfloat16* gb = Bb + (size_t)(call * 32 + rowL) * 512 + k0 + colSwz;
      GLOAD16(gb, (char*)sB + call * 4096 + wid * 1024);
    }
    __syncthreads();

    const bf16x8* pA = (const bf16x8*)sA;
    const bf16x8* pB = (const bf16x8*)sB;
    #pragma unroll
    for (int kk = 0; kk < 2; ++kk) {
      bf16x8 af[4], bfv[4];
      #pragma unroll
      for (int fi = 0; fi < 4; ++fi)
        af[fi] = pA[(wrow * 64 + fi * 16 + fr) * 8 + ((kk * 4 + fq) ^ (fr & 7))];
      #pragma unroll
      for (int fj = 0; fj < 4; ++fj)
        bfv[fj] = pB[(wcol * 64 + fj * 16 + fr) * 8 + ((kk * 4 + fq) ^ (fr & 7))];
      #pragma unroll
      for (int fi = 0; fi < 4; ++fi)
        #pragma unroll
        for (int fj = 0; fj < 4; ++fj)
          acc[fi][fj] = __builtin_amdgcn_mfma_f32_16x16x32_bf16(af[fi], bfv[fj], acc[fi][fj], 0, 0, 0);
    }
  }

  float g = 0.f;
  if (MODE == 2) g = gainp[0];

  #pragma unroll
  for (int fi = 0; fi < 4; ++fi) {
    #pragma unroll
    for (int fj = 0; fj < 4; ++fj) {
      #pragma unroll
      for (int jj = 0; jj < 4; ++jj) {
        const int gm = bm * 128 + wrow * 64 + fi * 16 + fq * 4 + jj;
        const int gn = bn * 128 + wcol * 64 + fj * 16 + fr;
        const float c = acc[fi][fj][jj];
        if constexpr (MODE == 0) {
          outp[(size_t)gm * ldo + gn] = f2b(c);
        } else if constexpr (MODE == 1) {
          const float y = MP_NEW * c + MP_RES * b2f(res[(size_t)gm * 512 + gn]);
          outp[(size_t)gm * ldo + gn] = f2b(y);
        } else {
          const float y = MP_NEW * (c * g) + MP_RES * b2f(res[(size_t)gm * 512 + gn]);
          outp[(size_t)gm * ldo + gn] = f2b(y);
        }
      }
    }
  }
}

extern "C" void kernel_launch(void* const* d_in, const int* in_sizes, int n_in,
                              void* d_out, int out_size, void* d_ws, size_t ws_size,
                              hipStream_t stream)
{
  const float* x     = (const float*)d_in[0];
  const float* wqkv  = (const float*)d_in[1];
  const float* wout  = (const float*)d_in[2];
  const float* mkv   = (const float*)d_in[3];
  const float* wproj = (const float*)d_in[4];
  const float* gain  = (const float*)d_in[5];
  float* out = (float*)d_out;

  // workspace layout (bytes), total 96,993,280 (< proven-available 117,964,800)
  char* ws = (char*)d_ws;
  __hip_bfloat16* Y0   = (__hip_bfloat16*)(ws + 0);           // 33,554,432
  __hip_bfloat16* Ycur = (__hip_bfloat16*)(ws + 33554432);    // 33,554,432
  __hip_bfloat16* QKVc = (__hip_bfloat16*)(ws + 67108864);    // 25,165,824 (8192x1536 bf16)
  __hip_bfloat16* WQ   = (__hip_bfloat16*)(ws + 92274688);    //  3,145,728
  __hip_bfloat16* WO   = (__hip_bfloat16*)(ws + 95420416);    //  1,048,576
  __hip_bfloat16* WP   = (__hip_bfloat16*)(ws + 96468992);    //    524,288

  if (ws_size < 96993280ULL) {
    fill_kernel<<<(out_size + 255) / 256, 256, 0, stream>>>(out, out_size);
    return;
  }

  wnorm_pack<<<3072, 64, 0, stream>>>(wqkv,  WQ);
  wnorm_pack<<<1024, 64, 0, stream>>>(wout,  WO);
  wnorm_pack<<<512,  64, 0, stream>>>(wproj, WP);

  transpose_in<<<dim3(32, 16, 32), dim3(32, 8), 0, stream>>>(x, Y0);

  const int M = 32768, CH = 8192, NCH = M / CH;
  for (int layer = 0; layer < 2; ++layer) {
    const __hip_bfloat16* WQl = WQ + (size_t)layer * 786432;
    const __hip_bfloat16* WOl = WO + (size_t)layer * 262144;
    const float* mk = mkv + (size_t)layer * 4096;
    __hip_bfloat16* Acur = (layer == 0) ? Y0 : Ycur;
    for (int ch = 0; ch < NCH; ++ch) {
      const size_t m0 = (size_t)ch * CH;
      gemm3<0><<<dim3(12, CH / 128), 256, 0, stream>>>(Acur + m0 * 512, WQl, 512,
                                                       QKVc, 1536, nullptr, nullptr);
      attn_kernel<<<CH / 16, 256, 0, stream>>>(QKVc, mk);
      gemm3<1><<<dim3(4, CH / 128), 256, 0, stream>>>(QKVc, WOl, 1536,
                                                      Ycur + m0 * 512, 512,
                                                      Acur + m0 * 512, nullptr);
    }
  }

  gemm3<2><<<dim3(4, 256), 256, 0, stream>>>(Ycur, WP, 512, Y0, 512, Y0, gain);
  transpose_out<<<dim3(32, 16, 32), dim3(32, 8), 0, stream>>>(Y0, out);
}

// Round 7
// 545.533 us; speedup vs baseline: 1.4575x; 1.4575x over previous
//
#include <hip/hip_runtime.h>
#include <hip/hip_bf16.h>

// MPAttentionInflationBlock on MI355X — round 7.
// = round 6 with one compile fix: `Vt[..] = mv[j]` was `__hip_bfloat16 = __bf16`
// (ambiguous operator=); now a bit-level `*(__bf16*)&Vt[..] = mv[j]`.
// Design: MFMA attention (QK^T and PV on the matrix pipe), fragment addressing
// copied from the proven gemm3; K/V slab 33KB; q read as A-frags from global
// with norm folded in post-MFMA; k normalized in place; V normalized+transposed
// to per-wave Vt; softmax kept in the proven serial form. GEMMs unchanged.

typedef __attribute__((ext_vector_type(8))) __bf16 bf16x8;
typedef __attribute__((ext_vector_type(4))) __bf16 bf16x4;
typedef __attribute__((ext_vector_type(4))) float  f32x4;

#define MP_NEW 0.9191450300180579f   // 0.7 / sqrt(0.58)
#define MP_RES 0.3939192985791677f   // 0.3 / sqrt(0.58)

__device__ __forceinline__ __hip_bfloat16 f2b(float x) { return __float2bfloat16(x); }
__device__ __forceinline__ float b2f(__hip_bfloat16 x) { return __bfloat162float(x); }

#define GLOAD16(g, l)                                                             \
  __builtin_amdgcn_global_load_lds((const __attribute__((address_space(1))) void*)(g), \
                                   (__attribute__((address_space(3))) void*)(l), 16, 0, 0)

// -------- diagnostic fallback: ws too small -> unmistakable output --------
__global__ __launch_bounds__(256)
void fill_kernel(float* o, int n)
{
  int i = blockIdx.x * 256 + threadIdx.x;
  if (i < n) o[i] = 12345.0f;
}

// -------- weight row-l2norm: wn = w/max(||w||,1e-4)/sqrt(512), f32->bf16 --------
__global__ __launch_bounds__(64)
void wnorm_pack(const float* __restrict__ w, __hip_bfloat16* __restrict__ o)
{
  const int r = blockIdx.x, lane = threadIdx.x;
  const float* wr = w + (size_t)r * 512;
  float x[8], s = 0.f;
  #pragma unroll
  for (int e = 0; e < 8; ++e) { x[e] = wr[e * 64 + lane]; s += x[e] * x[e]; }
  #pragma unroll
  for (int m = 1; m < 64; m <<= 1) s += __shfl_xor(s, m);
  const float scale = 1.0f / (fmaxf(sqrtf(s), 1e-4f) * 22.62741699796952f); // *sqrt(512)
  #pragma unroll
  for (int e = 0; e < 8; ++e) o[(size_t)r * 512 + e * 64 + lane] = f2b(x[e] * scale);
}

// -------- mem_kv pixel-norm prep (once; seq-invariant) --------
// mkv[l][kv][h][j][d] f32 -> KG[l][h][j][d] bf16 (k*8/||k||), VG[l][h][d][j] bf16
__global__ __launch_bounds__(64)
void memnorm(const float* __restrict__ mkv, __hip_bfloat16* __restrict__ KG,
             __hip_bfloat16* __restrict__ VG)
{
  const int vec = blockIdx.x;        // 0..127
  const int lane = threadIdx.x;      // = d
  const int l = vec >> 6, r = vec & 63;
  const int kv = r >> 5, h = (r >> 2) & 7, j = r & 3;
  const float x = mkv[l * 4096 + kv * 2048 + h * 256 + j * 64 + lane];
  float s = x * x;
  #pragma unroll
  for (int m = 1; m < 64; m <<= 1) s += __shfl_xor(s, m);
  const float v = x * (8.0f / fmaxf(sqrtf(s), 1e-4f));
  if (kv == 0) KG[((l * 8 + h) * 4 + j) * 64 + lane] = f2b(v);
  else         VG[((l * 8 + h) * 64 + lane) * 4 + j] = f2b(v);
}

// -------- x[b,c,t,h,w] (f32) -> Y0[m][c] (bf16 token-major) --------
__global__ __launch_bounds__(256)
void transpose_in(const float* __restrict__ x, __hip_bfloat16* __restrict__ Y0)
{
  __shared__ float tile[32][33];
  const int tx = threadIdx.x, ty = threadIdx.y;
  const int hh = blockIdx.x;
  const int c0 = blockIdx.y * 32;
  const int bt = blockIdx.z;
  const int b = bt >> 4, t = bt & 15;
  const float* xb = x + (size_t)b * 8388608 + (size_t)t * 1024 + hh * 32 + tx;
  #pragma unroll
  for (int r = 0; r < 4; ++r) {
    const int cc = ty * 4 + r;
    tile[tx][cc] = xb[(size_t)(c0 + cc) * 16384];
  }
  __syncthreads();
  #pragma unroll
  for (int r = 0; r < 4; ++r) {
    const int w = ty * 4 + r;
    const size_t m = ((size_t)b * 1024 + hh * 32 + w) * 16 + t;
    Y0[m * 512 + c0 + tx] = f2b(tile[w][tx]);
  }
}

// -------- Yf[m][c] (bf16) -> out[b,c,t,h,w] (f32) --------
__global__ __launch_bounds__(256)
void transpose_out(const __hip_bfloat16* __restrict__ Yf, float* __restrict__ out)
{
  __shared__ __align__(16) __hip_bfloat16 tile[32][33];
  const int tx = threadIdx.x, ty = threadIdx.y;
  const int hh = blockIdx.x;
  const int c0 = blockIdx.y * 32;
  const int bt = blockIdx.z;
  const int b = bt >> 4, t = bt & 15;
  #pragma unroll
  for (int r = 0; r < 4; ++r) {
    const int w = ty * 4 + r;
    const size_t m = ((size_t)b * 1024 + hh * 32 + w) * 16 + t;
    tile[w][tx] = Yf[m * 512 + c0 + tx];
  }
  __syncthreads();
  float* ob = out + (size_t)b * 8388608 + (size_t)t * 1024 + hh * 32 + tx;
  #pragma unroll
  for (int r = 0; r < 4; ++r) {
    const int cc = ty * 4 + r;
    ob[(size_t)(c0 + cc) * 16384] = b2f(tile[tx][cc]);
  }
}

// -------- MFMA attention: one block per seq, 4 waves x 2 heads --------
// QKV row: [q 0..511 | k 512..1023 | v 1024..1535]. slab stages k|v (1024
// cols, row stride 1032 elems). j index: 0..3 mem keys, 4..19 seq keys.
// Output overwrites the q-columns in place (disjoint per block/wave/head).
#define SLAB_LD 1032
#define VT_LD   40
#define PS_LD   33
__global__ __launch_bounds__(256)
void attn_kernel(__hip_bfloat16* __restrict__ QKV,
                 const __hip_bfloat16* __restrict__ KmemG,
                 const __hip_bfloat16* __restrict__ VmemTG)
{
  __shared__ __align__(16) __hip_bfloat16 slab[16 * SLAB_LD];   // 33,024 B
  __shared__ __align__(16) __hip_bfloat16 VtS[4][64 * VT_LD];   // 20,480 B
  __shared__ float PsS[4][16 * PS_LD];                          //  8,448 B
  __shared__ __align__(16) __hip_bfloat16 Kmem[2048];           //  4,096 B [h][j][d]
  __shared__ __align__(16) __hip_bfloat16 VmemT[2048];          //  4,096 B [h][d][j]
  const int tid = threadIdx.x;
  const int wid = tid >> 6, lane = tid & 63;
  const int seq = blockIdx.x;
  __hip_bfloat16* gbase = QKV + (size_t)seq * 16 * 1536;

  // ---- stage k|v slab: 32 x 1KB chunks, 8 per wave ----
  #pragma unroll
  for (int u = 0; u < 8; ++u) {
    const int o = wid * 8 + u;
    const int r = o >> 1, c = o & 1;
    GLOAD16(gbase + r * 1536 + 512 + c * 512 + lane * 8,
            (char*)slab + r * 2064 + c * 1024);
  }
  // ---- stage normalized mem k/v (4KB each, 8 chunks) ----
  #pragma unroll
  for (int u = 0; u < 2; ++u) {
    const int o = wid * 2 + u;
    if (o < 4) GLOAD16(KmemG + o * 512 + lane * 8, (char*)Kmem + o * 1024);
    else       GLOAD16(VmemTG + (o - 4) * 512 + lane * 8, (char*)VmemT + (o - 4) * 1024);
  }
  __syncthreads();

  __hip_bfloat16* Vt = VtS[wid];
  float* Ps = PsS[wid];
  const int jj = lane & 15;
  const int grp = lane >> 4;

  #pragma unroll
  for (int hh = 0; hh < 2; ++hh) {
    const int h = wid * 2 + hh;

    // ---- k/v pixel-norms, 4 rows per pass (16-lane groups) ----
    // k: scale in place (bf16). v: scale + transpose into Vt cols 4..19.
    #pragma unroll
    for (int p = 0; p < 8; ++p) {
      const int kvv = p >> 2;
      const int j = (p & 3) * 4 + grp;
      const int col = kvv * 512 + h * 64 + jj * 4;
      bf16x4 x4 = *(const bf16x4*)&slab[j * SLAB_LD + col];
      const float f0 = (float)x4[0], f1 = (float)x4[1];
      const float f2 = (float)x4[2], f3 = (float)x4[3];
      float s = f0 * f0 + f1 * f1 + f2 * f2 + f3 * f3;
      s += __shfl_xor(s, 1); s += __shfl_xor(s, 2);
      s += __shfl_xor(s, 4); s += __shfl_xor(s, 8);
      const float sc = 8.0f / fmaxf(sqrtf(s), 1e-4f);
      if (kvv == 0) {
        bf16x4 w4;
        w4[0] = (__bf16)(f0 * sc); w4[1] = (__bf16)(f1 * sc);
        w4[2] = (__bf16)(f2 * sc); w4[3] = (__bf16)(f3 * sc);
        *(bf16x4*)&slab[j * SLAB_LD + col] = w4;
      } else {
        Vt[(jj * 4 + 0) * VT_LD + 4 + j] = f2b(f0 * sc);
        Vt[(jj * 4 + 1) * VT_LD + 4 + j] = f2b(f1 * sc);
        Vt[(jj * 4 + 2) * VT_LD + 4 + j] = f2b(f2 * sc);
        Vt[(jj * 4 + 3) * VT_LD + 4 + j] = f2b(f3 * sc);
      }
    }
    // mem V -> Vt cols 0..3 (lane = d); bit-level store (avoid ambiguous op=)
    {
      bf16x4 mv = *(const bf16x4*)&VmemT[h * 256 + lane * 4];
      #pragma unroll
      for (int j = 0; j < 4; ++j) *(__bf16*)&Vt[lane * VT_LD + j] = mv[j];
    }
    // zero Vt pad cols 20..31 (row = lane)
    #pragma unroll
    for (int z = 0; z < 6; ++z)
      *(unsigned int*)&Vt[lane * VT_LD + 20 + z * 2] = 0u;
    // zero Ps pad cols 20..31
    #pragma unroll
    for (int z = 0; z < 3; ++z)
      Ps[(lane >> 2) * PS_LD + 20 + (lane & 3) * 3 + z] = 0.f;

    // ---- Q A-frags from global + row-norm scale ----
    const __hip_bfloat16* qg = gbase + (size_t)jj * 1536 + h * 64 + grp * 8;
    const bf16x8 qa0 = *(const bf16x8*)qg;
    const bf16x8 qa1 = *(const bf16x8*)(qg + 32);
    float qs = 0.f;
    #pragma unroll
    for (int e = 0; e < 8; ++e) {
      const float a0 = (float)qa0[e], a1 = (float)qa1[e];
      qs += a0 * a0 + a1 * a1;
    }
    qs += __shfl_xor(qs, 16); qs += __shfl_xor(qs, 32);
    const float qscale = 1.0f / fmaxf(sqrtf(qs), 1e-4f);   // on lanes with (lane&15)==row

    // ---- QK^T: sim[16][20] via 4 mfma (2 j-tiles x 2 k-steps) ----
    f32x4 s0 = {0.f, 0.f, 0.f, 0.f}, s1 = {0.f, 0.f, 0.f, 0.f};
    #pragma unroll
    for (int kk = 0; kk < 2; ++kk) {
      const int koff = kk * 32 + grp * 8;
      const bf16x8 a = kk ? qa1 : qa0;
      const __hip_bfloat16* bp0 = (jj < 4)
          ? &Kmem[(h * 4 + jj) * 64 + koff]
          : &slab[(jj - 4) * SLAB_LD + h * 64 + koff];
      const bf16x8 b0 = *(const bf16x8*)bp0;
      bf16x8 b1 = *(const bf16x8*)&slab[(12 + (jj & 3)) * SLAB_LD + h * 64 + koff];
      if (jj >= 4) {
        #pragma unroll
        for (int e = 0; e < 8; ++e) b1[e] = (__bf16)0.f;
      }
      s0 = __builtin_amdgcn_mfma_f32_16x16x32_bf16(a, b0, s0, 0, 0, 0);
      s1 = __builtin_amdgcn_mfma_f32_16x16x32_bf16(a, b1, s1, 0, 0, 0);
    }

    // ---- C-frags * qscale -> Ps[row][j] (f32) ----
    #pragma unroll
    for (int r = 0; r < 4; ++r) {
      const int row = grp * 4 + r;
      const float sc = __shfl(qscale, row);       // lane 'row' holds row's qscale
      Ps[row * PS_LD + jj] = s0[r] * sc;
      if (jj < 4) Ps[row * PS_LD + 16 + jj] = s1[r] * sc;
    }

    // ---- row softmax (proven serial form; lanes 0..15) ----
    if (lane < 16) {
      float mx = -1e30f;
      #pragma unroll
      for (int j = 0; j < 20; ++j) mx = fmaxf(mx, Ps[lane * PS_LD + j]);
      float e[20], ssum = 0.f;
      #pragma unroll
      for (int j = 0; j < 20; ++j) { e[j] = expf(Ps[lane * PS_LD + j] - mx); ssum += e[j]; }
      const float inv = 1.0f / ssum;
      #pragma unroll
      for (int j = 0; j < 20; ++j) Ps[lane * PS_LD + j] = e[j] * inv;
    }

    // ---- P A-frag (row = jj, j = grp*8..+7; pads are zero) ----
    bf16x8 pa;
    #pragma unroll
    for (int e = 0; e < 8; ++e) {
      const __hip_bfloat16 t = f2b(Ps[jj * PS_LD + grp * 8 + e]);
      pa[e] = *(const __bf16*)&t;
    }

    // ---- PV: out[16][64] via 4 mfma; store to global q-cols ----
    #pragma unroll
    for (int t = 0; t < 4; ++t) {
      const bf16x8 vb = *(const bf16x8*)&Vt[(t * 16 + jj) * VT_LD + grp * 8];
      f32x4 o = {0.f, 0.f, 0.f, 0.f};
      o = __builtin_amdgcn_mfma_f32_16x16x32_bf16(pa, vb, o, 0, 0, 0);
      #pragma unroll
      for (int r = 0; r < 4; ++r)
        gbase[(size_t)(grp * 4 + r) * 1536 + h * 64 + t * 16 + jj] = f2b(o[r]);
    }
  }
}

// -------- bf16 gemm_bt: C[m][n] = sum_k A[m][k]*Bw[n][k], K=512, 128x128 tile --------
// T2 swizzle both-sides (rule #21); T1 XCD block swizzle. (unchanged, passing)
template<int MODE>
__global__ __launch_bounds__(256)
void gemm3(const __hip_bfloat16* __restrict__ A, const __hip_bfloat16* __restrict__ Bw,
           int lda, __hip_bfloat16* __restrict__ outp, int ldo,
           const __hip_bfloat16* __restrict__ res, const float* __restrict__ gainp)
{
  __shared__ __hip_bfloat16 sA[128 * 64];
  __shared__ __hip_bfloat16 sB[128 * 64];
  const int nwg = gridDim.x * gridDim.y;
  int bid = blockIdx.y * gridDim.x + blockIdx.x;
  bid = (bid & 7) * (nwg >> 3) + (bid >> 3);
  const int bn = bid % gridDim.x, bm = bid / gridDim.x;

  const int tid = threadIdx.x;
  const int wid = tid >> 6, lane = tid & 63;
  const int wrow = wid >> 1, wcol = wid & 1;
  const int fr = lane & 15, fq = lane >> 4;
  const int rowL = tid >> 3;
  const int colSwz = (((tid & 7) ^ (rowL & 7)) * 8);

  const __hip_bfloat16* Ab = A  + (size_t)bm * 128 * lda;
  const __hip_bfloat16* Bb = Bw + (size_t)bn * 128 * 512;

  f32x4 acc[4][4];
  const f32x4 zz = {0.f, 0.f, 0.f, 0.f};
  #pragma unroll
  for (int i = 0; i < 4; ++i)
    #pragma unroll
    for (int j = 0; j < 4; ++j) acc[i][j] = zz;

  for (int ks = 0; ks < 8; ++ks) {
    const int k0 = ks * 64;
    __syncthreads();
    #pragma unroll
    for (int call = 0; call < 4; ++call) {
      const __hip_bfloat16* ga = Ab + (size_t)(call * 32 + rowL) * lda + k0 + colSwz;
      GLOAD16(ga, (char*)sA + call * 4096 + wid * 1024);
    }
    #pragma unroll
    for (int call = 0; call < 4; ++call) {
      const __hip_bfloat16* gb = Bb + (size_t)(call * 32 + rowL) * 512 + k0 + colSwz;
      GLOAD16(gb, (char*)sB + call * 4096 + wid * 1024);
    }
    __syncthreads();

    const bf16x8* pA = (const bf16x8*)sA;
    const bf16x8* pB = (const bf16x8*)sB;
    #pragma unroll
    for (int kk = 0; kk < 2; ++kk) {
      bf16x8 af[4], bfv[4];
      #pragma unroll
      for (int fi = 0; fi < 4; ++fi)
        af[fi] = pA[(wrow * 64 + fi * 16 + fr) * 8 + ((kk * 4 + fq) ^ (fr & 7))];
      #pragma unroll
      for (int fj = 0; fj < 4; ++fj)
        bfv[fj] = pB[(wcol * 64 + fj * 16 + fr) * 8 + ((kk * 4 + fq) ^ (fr & 7))];
      #pragma unroll
      for (int fi = 0; fi < 4; ++fi)
        #pragma unroll
        for (int fj = 0; fj < 4; ++fj)
          acc[fi][fj] = __builtin_amdgcn_mfma_f32_16x16x32_bf16(af[fi], bfv[fj], acc[fi][fj], 0, 0, 0);
    }
  }

  float g = 0.f;
  if (MODE == 2) g = gainp[0];

  #pragma unroll
  for (int fi = 0; fi < 4; ++fi) {
    #pragma unroll
    for (int fj = 0; fj < 4; ++fj) {
      #pragma unroll
      for (int jj2 = 0; jj2 < 4; ++jj2) {
        const int gm = bm * 128 + wrow * 64 + fi * 16 + fq * 4 + jj2;
        const int gn = bn * 128 + wcol * 64 + fj * 16 + fr;
        const float c = acc[fi][fj][jj2];
        if constexpr (MODE == 0) {
          outp[(size_t)gm * ldo + gn] = f2b(c);
        } else if constexpr (MODE == 1) {
          const float y = MP_NEW * c + MP_RES * b2f(res[(size_t)gm * 512 + gn]);
          outp[(size_t)gm * ldo + gn] = f2b(y);
        } else {
          const float y = MP_NEW * (c * g) + MP_RES * b2f(res[(size_t)gm * 512 + gn]);
          outp[(size_t)gm * ldo + gn] = f2b(y);
        }
      }
    }
  }
}

extern "C" void kernel_launch(void* const* d_in, const int* in_sizes, int n_in,
                              void* d_out, int out_size, void* d_ws, size_t ws_size,
                              hipStream_t stream)
{
  const float* x     = (const float*)d_in[0];
  const float* wqkv  = (const float*)d_in[1];
  const float* wout  = (const float*)d_in[2];
  const float* mkv   = (const float*)d_in[3];
  const float* wproj = (const float*)d_in[4];
  const float* gain  = (const float*)d_in[5];
  float* out = (float*)d_out;

  // workspace layout (bytes), total 97,009,664 (< proven-available 117,964,800)
  char* ws = (char*)d_ws;
  __hip_bfloat16* Y0     = (__hip_bfloat16*)(ws + 0);          // 33,554,432
  __hip_bfloat16* Ycur   = (__hip_bfloat16*)(ws + 33554432);   // 33,554,432
  __hip_bfloat16* QKVc   = (__hip_bfloat16*)(ws + 67108864);   // 25,165,824 (8192x1536)
  __hip_bfloat16* WQ     = (__hip_bfloat16*)(ws + 92274688);   //  3,145,728
  __hip_bfloat16* WO     = (__hip_bfloat16*)(ws + 95420416);   //  1,048,576
  __hip_bfloat16* WP     = (__hip_bfloat16*)(ws + 96468992);   //    524,288
  __hip_bfloat16* KmemG  = (__hip_bfloat16*)(ws + 96993280);   //      8,192 (2 layers)
  __hip_bfloat16* VmemTG = (__hip_bfloat16*)(ws + 97001472);   //      8,192

  if (ws_size < 97009664ULL) {
    fill_kernel<<<(out_size + 255) / 256, 256, 0, stream>>>(out, out_size);
    return;
  }

  wnorm_pack<<<3072, 64, 0, stream>>>(wqkv,  WQ);
  wnorm_pack<<<1024, 64, 0, stream>>>(wout,  WO);
  wnorm_pack<<<512,  64, 0, stream>>>(wproj, WP);
  memnorm<<<128, 64, 0, stream>>>(mkv, KmemG, VmemTG);

  transpose_in<<<dim3(32, 16, 32), dim3(32, 8), 0, stream>>>(x, Y0);

  const int M = 32768, CH = 8192, NCH = M / CH;
  for (int layer = 0; layer < 2; ++layer) {
    const __hip_bfloat16* WQl = WQ + (size_t)layer * 786432;
    const __hip_bfloat16* WOl = WO + (size_t)layer * 262144;
    __hip_bfloat16* Acur = (layer == 0) ? Y0 : Ycur;
    for (int ch = 0; ch < NCH; ++ch) {
      const size_t m0 = (size_t)ch * CH;
      gemm3<0><<<dim3(12, CH / 128), 256, 0, stream>>>(Acur + m0 * 512, WQl, 512,
                                                       QKVc, 1536, nullptr, nullptr);
      attn_kernel<<<CH / 16, 256, 0, stream>>>(QKVc, KmemG + (size_t)layer * 2048,
                                               VmemTG + (size_t)layer * 2048);
      gemm3<1><<<dim3(4, CH / 128), 256, 0, stream>>>(QKVc, WOl, 1536,
                                                      Ycur + m0 * 512, 512,
                                                      Acur + m0 * 512, nullptr);
    }
  }

  gemm3<2><<<dim3(4, 256), 256, 0, stream>>>(Ycur, WP, 512, Y0, 512, Y0, gain);
  transpose_out<<<dim3(32, 16, 32), dim3(32, 8), 0, stream>>>(Y0, out);
}

// Round 9
// 459.845 us; speedup vs baseline: 1.7291x; 1.1863x over previous
//
#include <hip/hip_runtime.h>
#include <hip/hip_bf16.h>

// MPAttentionInflationBlock on MI355X — round 9 (= round 8 resubmitted; that
// round died to an infra container failure with no measurement).
// vs round 7 (passed, 545us): (1) ws_size measured at 256MiB via the harness
// poison-fill counters -> tiered layout, unchunked layer processing (CH=32768)
// when it fits (3 dispatches/layer instead of 12; chunked fallbacks kept);
// (2) pixel-norm fused into gemm<0>'s epilogue (per-head 64-col groups are
// wcol-local: 4 squares + 4 shfl_xor per row), attention loses its whole
// norm phase (k direct from slab, Vt = pure transpose, no qscale).

typedef __attribute__((ext_vector_type(8))) __bf16 bf16x8;
typedef __attribute__((ext_vector_type(4))) __bf16 bf16x4;
typedef __attribute__((ext_vector_type(4))) float  f32x4;

#define MP_NEW 0.9191450300180579f   // 0.7 / sqrt(0.58)
#define MP_RES 0.3939192985791677f   // 0.3 / sqrt(0.58)

__device__ __forceinline__ __hip_bfloat16 f2b(float x) { return __float2bfloat16(x); }
__device__ __forceinline__ float b2f(__hip_bfloat16 x) { return __bfloat162float(x); }

#define GLOAD16(g, l)                                                             \
  __builtin_amdgcn_global_load_lds((const __attribute__((address_space(1))) void*)(g), \
                                   (__attribute__((address_space(3))) void*)(l), 16, 0, 0)

// -------- diagnostic fallback: ws too small -> unmistakable output --------
__global__ __launch_bounds__(256)
void fill_kernel(float* o, int n)
{
  int i = blockIdx.x * 256 + threadIdx.x;
  if (i < n) o[i] = 12345.0f;
}

// -------- weight row-l2norm: wn = w/max(||w||,1e-4)/sqrt(512), f32->bf16 --------
__global__ __launch_bounds__(64)
void wnorm_pack(const float* __restrict__ w, __hip_bfloat16* __restrict__ o)
{
  const int r = blockIdx.x, lane = threadIdx.x;
  const float* wr = w + (size_t)r * 512;
  float x[8], s = 0.f;
  #pragma unroll
  for (int e = 0; e < 8; ++e) { x[e] = wr[e * 64 + lane]; s += x[e] * x[e]; }
  #pragma unroll
  for (int m = 1; m < 64; m <<= 1) s += __shfl_xor(s, m);
  const float scale = 1.0f / (fmaxf(sqrtf(s), 1e-4f) * 22.62741699796952f); // *sqrt(512)
  #pragma unroll
  for (int e = 0; e < 8; ++e) o[(size_t)r * 512 + e * 64 + lane] = f2b(x[e] * scale);
}

// -------- mem_kv pixel-norm prep (once; seq-invariant) --------
// mkv[l][kv][h][j][d] f32 -> KG[l][h][j][d] bf16 (k*8/||k||), VG[l][h][d][j] bf16
__global__ __launch_bounds__(64)
void memnorm(const float* __restrict__ mkv, __hip_bfloat16* __restrict__ KG,
             __hip_bfloat16* __restrict__ VG)
{
  const int vec = blockIdx.x;        // 0..127
  const int lane = threadIdx.x;      // = d
  const int l = vec >> 6, r = vec & 63;
  const int kv = r >> 5, h = (r >> 2) & 7, j = r & 3;
  const float x = mkv[l * 4096 + kv * 2048 + h * 256 + j * 64 + lane];
  float s = x * x;
  #pragma unroll
  for (int m = 1; m < 64; m <<= 1) s += __shfl_xor(s, m);
  const float v = x * (8.0f / fmaxf(sqrtf(s), 1e-4f));
  if (kv == 0) KG[((l * 8 + h) * 4 + j) * 64 + lane] = f2b(v);
  else         VG[((l * 8 + h) * 64 + lane) * 4 + j] = f2b(v);
}

// -------- x[b,c,t,h,w] (f32) -> Y0[m][c] (bf16 token-major) --------
__global__ __launch_bounds__(256)
void transpose_in(const float* __restrict__ x, __hip_bfloat16* __restrict__ Y0)
{
  __shared__ float tile[32][33];
  const int tx = threadIdx.x, ty = threadIdx.y;
  const int hh = blockIdx.x;
  const int c0 = blockIdx.y * 32;
  const int bt = blockIdx.z;
  const int b = bt >> 4, t = bt & 15;
  const float* xb = x + (size_t)b * 8388608 + (size_t)t * 1024 + hh * 32 + tx;
  #pragma unroll
  for (int r = 0; r < 4; ++r) {
    const int cc = ty * 4 + r;
    tile[tx][cc] = xb[(size_t)(c0 + cc) * 16384];
  }
  __syncthreads();
  #pragma unroll
  for (int r = 0; r < 4; ++r) {
    const int w = ty * 4 + r;
    const size_t m = ((size_t)b * 1024 + hh * 32 + w) * 16 + t;
    Y0[m * 512 + c0 + tx] = f2b(tile[w][tx]);
  }
}

// -------- Yf[m][c] (bf16) -> out[b,c,t,h,w] (f32) --------
__global__ __launch_bounds__(256)
void transpose_out(const __hip_bfloat16* __restrict__ Yf, float* __restrict__ out)
{
  __shared__ __align__(16) __hip_bfloat16 tile[32][33];
  const int tx = threadIdx.x, ty = threadIdx.y;
  const int hh = blockIdx.x;
  const int c0 = blockIdx.y * 32;
  const int bt = blockIdx.z;
  const int b = bt >> 4, t = bt & 15;
  #pragma unroll
  for (int r = 0; r < 4; ++r) {
    const int w = ty * 4 + r;
    const size_t m = ((size_t)b * 1024 + hh * 32 + w) * 16 + t;
    tile[w][tx] = Yf[m * 512 + c0 + tx];
  }
  __syncthreads();
  float* ob = out + (size_t)b * 8388608 + (size_t)t * 1024 + hh * 32 + tx;
  #pragma unroll
  for (int r = 0; r < 4; ++r) {
    const int cc = ty * 4 + r;
    ob[(size_t)(c0 + cc) * 16384] = b2f(tile[tx][cc]);
  }
}

// -------- MFMA attention: one block per seq, 4 waves x 2 heads --------
// QKV row: [q 0..511 | k 512..1023 | v 1024..1535], ALL pre-normalized by
// gemm<0>'s epilogue. slab stages k|v (slab col 0..511 = k, 512..1023 = v).
// j index: 0..3 mem keys, 4..19 seq keys. Output overwrites q-cols in place.
#define SLAB_LD 1032
#define VT_LD   40
#define PS_LD   33
__global__ __launch_bounds__(256)
void attn_kernel(__hip_bfloat16* __restrict__ QKV,
                 const __hip_bfloat16* __restrict__ KmemG,
                 const __hip_bfloat16* __restrict__ VmemTG)
{
  __shared__ __align__(16) __hip_bfloat16 slab[16 * SLAB_LD];   // 33,024 B
  __shared__ __align__(16) __hip_bfloat16 VtS[4][64 * VT_LD];   // 20,480 B
  __shared__ float PsS[4][16 * PS_LD];                          //  8,448 B
  __shared__ __align__(16) __hip_bfloat16 Kmem[2048];           //  4,096 B [h][j][d]
  __shared__ __align__(16) __hip_bfloat16 VmemT[2048];          //  4,096 B [h][d][j]
  const int tid = threadIdx.x;
  const int wid = tid >> 6, lane = tid & 63;
  const int seq = blockIdx.x;
  __hip_bfloat16* gbase = QKV + (size_t)seq * 16 * 1536;

  // ---- stage k|v slab: 32 x 1KB chunks, 8 per wave ----
  #pragma unroll
  for (int u = 0; u < 8; ++u) {
    const int o = wid * 8 + u;
    const int r = o >> 1, c = o & 1;
    GLOAD16(gbase + r * 1536 + 512 + c * 512 + lane * 8,
            (char*)slab + r * 2064 + c * 1024);
  }
  // ---- stage normalized mem k/v (4KB each, 8 chunks) ----
  #pragma unroll
  for (int u = 0; u < 2; ++u) {
    const int o = wid * 2 + u;
    if (o < 4) GLOAD16(KmemG + o * 512 + lane * 8, (char*)Kmem + o * 1024);
    else       GLOAD16(VmemTG + (o - 4) * 512 + lane * 8, (char*)VmemT + (o - 4) * 1024);
  }
  __syncthreads();

  __hip_bfloat16* Vt = VtS[wid];
  float* Ps = PsS[wid];
  const int jj = lane & 15;
  const int grp = lane >> 4;

  #pragma unroll
  for (int hh = 0; hh < 2; ++hh) {
    const int h = wid * 2 + hh;

    // ---- V transpose into Vt cols 4..19 (already normalized; 4 rows/pass) ----
    #pragma unroll
    for (int p = 0; p < 4; ++p) {
      const int j = p * 4 + grp;
      const int col = 512 + h * 64 + jj * 4;       // slab v region
      bf16x4 x4 = *(const bf16x4*)&slab[j * SLAB_LD + col];
      *(__bf16*)&Vt[(jj * 4 + 0) * VT_LD + 4 + j] = x4[0];
      *(__bf16*)&Vt[(jj * 4 + 1) * VT_LD + 4 + j] = x4[1];
      *(__bf16*)&Vt[(jj * 4 + 2) * VT_LD + 4 + j] = x4[2];
      *(__bf16*)&Vt[(jj * 4 + 3) * VT_LD + 4 + j] = x4[3];
    }
    // mem V -> Vt cols 0..3 (lane = d)
    {
      bf16x4 mv = *(const bf16x4*)&VmemT[h * 256 + lane * 4];
      #pragma unroll
      for (int j = 0; j < 4; ++j) *(__bf16*)&Vt[lane * VT_LD + j] = mv[j];
    }
    // zero Vt pad cols 20..31 (row = lane)
    #pragma unroll
    for (int z = 0; z < 6; ++z)
      *(unsigned int*)&Vt[lane * VT_LD + 20 + z * 2] = 0u;
    // zero Ps pad cols 20..31
    #pragma unroll
    for (int z = 0; z < 3; ++z)
      Ps[(lane >> 2) * PS_LD + 20 + (lane & 3) * 3 + z] = 0.f;

    // ---- Q A-frags from global (pre-normalized) ----
    const __hip_bfloat16* qg = gbase + (size_t)jj * 1536 + h * 64 + grp * 8;
    const bf16x8 qa0 = *(const bf16x8*)qg;
    const bf16x8 qa1 = *(const bf16x8*)(qg + 32);

    // ---- QK^T: sim[16][20] via 4 mfma (2 j-tiles x 2 k-steps) ----
    f32x4 s0 = {0.f, 0.f, 0.f, 0.f}, s1 = {0.f, 0.f, 0.f, 0.f};
    #pragma unroll
    for (int kk = 0; kk < 2; ++kk) {
      const int koff = kk * 32 + grp * 8;
      const bf16x8 a = kk ? qa1 : qa0;
      const __hip_bfloat16* bp0 = (jj < 4)
          ? &Kmem[(h * 4 + jj) * 64 + koff]
          : &slab[(jj - 4) * SLAB_LD + h * 64 + koff];   // slab k region
      const bf16x8 b0 = *(const bf16x8*)bp0;
      bf16x8 b1 = *(const bf16x8*)&slab[(12 + (jj & 3)) * SLAB_LD + h * 64 + koff];
      if (jj >= 4) {
        #pragma unroll
        for (int e = 0; e < 8; ++e) b1[e] = (__bf16)0.f;
      }
      s0 = __builtin_amdgcn_mfma_f32_16x16x32_bf16(a, b0, s0, 0, 0, 0);
      s1 = __builtin_amdgcn_mfma_f32_16x16x32_bf16(a, b1, s1, 0, 0, 0);
    }

    // ---- C-frags -> Ps[row][j] (f32; no scale needed) ----
    #pragma unroll
    for (int r = 0; r < 4; ++r) {
      const int row = grp * 4 + r;
      Ps[row * PS_LD + jj] = s0[r];
      if (jj < 4) Ps[row * PS_LD + 16 + jj] = s1[r];
    }

    // ---- row softmax (proven serial form; lanes 0..15) ----
    if (lane < 16) {
      float mx = -1e30f;
      #pragma unroll
      for (int j = 0; j < 20; ++j) mx = fmaxf(mx, Ps[lane * PS_LD + j]);
      float e[20], ssum = 0.f;
      #pragma unroll
      for (int j = 0; j < 20; ++j) { e[j] = expf(Ps[lane * PS_LD + j] - mx); ssum += e[j]; }
      const float inv = 1.0f / ssum;
      #pragma unroll
      for (int j = 0; j < 20; ++j) Ps[lane * PS_LD + j] = e[j] * inv;
    }

    // ---- P A-frag (row = jj, j = grp*8..+7; pads are zero) ----
    bf16x8 pa;
    #pragma unroll
    for (int e = 0; e < 8; ++e) {
      const __hip_bfloat16 t = f2b(Ps[jj * PS_LD + grp * 8 + e]);
      pa[e] = *(const __bf16*)&t;
    }

    // ---- PV: out[16][64] via 4 mfma; store to global q-cols ----
    #pragma unroll
    for (int t = 0; t < 4; ++t) {
      const bf16x8 vb = *(const bf16x8*)&Vt[(t * 16 + jj) * VT_LD + grp * 8];
      f32x4 o = {0.f, 0.f, 0.f, 0.f};
      o = __builtin_amdgcn_mfma_f32_16x16x32_bf16(pa, vb, o, 0, 0, 0);
      #pragma unroll
      for (int r = 0; r < 4; ++r)
        gbase[(size_t)(grp * 4 + r) * 1536 + h * 64 + t * 16 + jj] = f2b(o[r]);
    }
  }
}

// -------- bf16 gemm_bt: C[m][n] = sum_k A[m][k]*Bw[n][k], K=512, 128x128 tile --------
// T2 swizzle both-sides (rule #21); T1 XCD block swizzle.
// MODE 0: out = pixel_norm(C) per (row, head-64-col group)   [QKV, ldo=1536]
//         scale = (bn<4 ? 1 : 8) / max(||row-head||, 1e-4)   (q|k|v regions)
// MODE 1: out = MP_NEW*C + MP_RES*res                        [out-proj, ldo=512]
// MODE 2: out = MP_NEW*(C*gain) + MP_RES*res                 [final proj]
template<int MODE>
__global__ __launch_bounds__(256)
void gemm3(const __hip_bfloat16* __restrict__ A, const __hip_bfloat16* __restrict__ Bw,
           int lda, __hip_bfloat16* __restrict__ outp, int ldo,
           const __hip_bfloat16* __restrict__ res, const float* __restrict__ gainp)
{
  __shared__ __hip_bfloat16 sA[128 * 64];
  __shared__ __hip_bfloat16 sB[128 * 64];
  const int nwg = gridDim.x * gridDim.y;
  int bid = blockIdx.y * gridDim.x + blockIdx.x;
  bid = (bid & 7) * (nwg >> 3) + (bid >> 3);
  const int bn = bid % gridDim.x, bm = bid / gridDim.x;

  const int tid = threadIdx.x;
  const int wid = tid >> 6, lane = tid & 63;
  const int wrow = wid >> 1, wcol = wid & 1;
  const int fr = lane & 15, fq = lane >> 4;
  const int rowL = tid >> 3;
  const int colSwz = (((tid & 7) ^ (rowL & 7)) * 8);

  const __hip_bfloat16* Ab = A  + (size_t)bm * 128 * lda;
  const __hip_bfloat16* Bb = Bw + (size_t)bn * 128 * 512;

  f32x4 acc[4][4];
  const f32x4 zz = {0.f, 0.f, 0.f, 0.f};
  #pragma unroll
  for (int i = 0; i < 4; ++i)
    #pragma unroll
    for (int j = 0; j < 4; ++j) acc[i][j] = zz;

  for (int ks = 0; ks < 8; ++ks) {
    const int k0 = ks * 64;
    __syncthreads();
    #pragma unroll
    for (int call = 0; call < 4; ++call) {
      const __hip_bfloat16* ga = Ab + (size_t)(call * 32 + rowL) * lda + k0 + colSwz;
      GLOAD16(ga, (char*)sA + call * 4096 + wid * 1024);
    }
    #pragma unroll
    for (int call = 0; call < 4; ++call) {
      const __hip_bfloat16* gb = Bb + (size_t)(call * 32 + rowL) * 512 + k0 + colSwz;
      GLOAD16(gb, (char*)sB + call * 4096 + wid * 1024);
    }
    __syncthreads();

    const bf16x8* pA = (const bf16x8*)sA;
    const bf16x8* pB = (const bf16x8*)sB;
    #pragma unroll
    for (int kk = 0; kk < 2; ++kk) {
      bf16x8 af[4], bfv[4];
      #pragma unroll
      for (int fi = 0; fi < 4; ++fi)
        af[fi] = pA[(wrow * 64 + fi * 16 + fr) * 8 + ((kk * 4 + fq) ^ (fr & 7))];
      #pragma unroll
      for (int fj = 0; fj < 4; ++fj)
        bfv[fj] = pB[(wcol * 64 + fj * 16 + fr) * 8 + ((kk * 4 + fq) ^ (fr & 7))];
      #pragma unroll
      for (int fi = 0; fi < 4; ++fi)
        #pragma unroll
        for (int fj = 0; fj < 4; ++fj)
          acc[fi][fj] = __builtin_amdgcn_mfma_f32_16x16x32_bf16(af[fi], bfv[fj], acc[fi][fj], 0, 0, 0);
    }
  }

  if constexpr (MODE == 0) {
    // per-head pixel-norm epilogue: head = this wcol's 64 cols; row = (fi,jj)
    const float num = (bn < 4) ? 1.0f : 8.0f;     // q region (cols<512) vs k,v
    #pragma unroll
    for (int fi = 0; fi < 4; ++fi) {
      #pragma unroll
      for (int jj2 = 0; jj2 < 4; ++jj2) {
        float ss = 0.f;
        #pragma unroll
        for (int fj = 0; fj < 4; ++fj) { const float c = acc[fi][fj][jj2]; ss += c * c; }
        ss += __shfl_xor(ss, 1); ss += __shfl_xor(ss, 2);
        ss += __shfl_xor(ss, 4); ss += __shfl_xor(ss, 8);   // sum over 16 fr-lanes
        const float sc = num / fmaxf(sqrtf(ss), 1e-4f);
        const int gm = bm * 128 + wrow * 64 + fi * 16 + fq * 4 + jj2;
        #pragma unroll
        for (int fj = 0; fj < 4; ++fj) {
          const int gn = bn * 128 + wcol * 64 + fj * 16 + fr;
          outp[(size_t)gm * ldo + gn] = f2b(acc[fi][fj][jj2] * sc);
        }
      }
    }
  } else {
    float g = 0.f;
    if (MODE == 2) g = gainp[0];
    #pragma unroll
    for (int fi = 0; fi < 4; ++fi) {
      #pragma unroll
      for (int fj = 0; fj < 4; ++fj) {
        #pragma unroll
        for (int jj2 = 0; jj2 < 4; ++jj2) {
          const int gm = bm * 128 + wrow * 64 + fi * 16 + fq * 4 + jj2;
          const int gn = bn * 128 + wcol * 64 + fj * 16 + fr;
          const float c = acc[fi][fj][jj2];
          if constexpr (MODE == 1) {
            const float y = MP_NEW * c + MP_RES * b2f(res[(size_t)gm * 512 + gn]);
            outp[(size_t)gm * ldo + gn] = f2b(y);
          } else {
            const float y = MP_NEW * (c * g) + MP_RES * b2f(res[(size_t)gm * 512 + gn]);
            outp[(size_t)gm * ldo + gn] = f2b(y);
          }
        }
      }
    }
  }
}

extern "C" void kernel_launch(void* const* d_in, const int* in_sizes, int n_in,
                              void* d_out, int out_size, void* d_ws, size_t ws_size,
                              hipStream_t stream)
{
  const float* x     = (const float*)d_in[0];
  const float* wqkv  = (const float*)d_in[1];
  const float* wout  = (const float*)d_in[2];
  const float* mkv   = (const float*)d_in[3];
  const float* wproj = (const float*)d_in[4];
  const float* gain  = (const float*)d_in[5];
  float* out = (float*)d_out;

  // tiered workspace: pick largest CH whose layout fits ws_size.
  // (round-7 profile: harness poison fill writes 256MiB -> ws expected 268,435,456)
  const size_t SZ_Y = 33554432;   // 32768 x 512 bf16
  int CH;
  if      (ws_size >= 2 * SZ_Y + (size_t)32768 * 1536 * 2 + 4734976) CH = 32768;
  else if (ws_size >= 2 * SZ_Y + (size_t)16384 * 1536 * 2 + 4734976) CH = 16384;
  else if (ws_size >= 2 * SZ_Y + (size_t)8192  * 1536 * 2 + 4734976) CH = 8192;
  else {
    fill_kernel<<<(out_size + 255) / 256, 256, 0, stream>>>(out, out_size);
    return;
  }
  const size_t qkv_bytes = (size_t)CH * 1536 * 2;
  char* ws = (char*)d_ws;
  __hip_bfloat16* Y0     = (__hip_bfloat16*)(ws + 0);
  __hip_bfloat16* Ycur   = (__hip_bfloat16*)(ws + SZ_Y);
  __hip_bfloat16* QKVc   = (__hip_bfloat16*)(ws + 2 * SZ_Y);
  __hip_bfloat16* WQ     = (__hip_bfloat16*)(ws + 2 * SZ_Y + qkv_bytes);
  __hip_bfloat16* WO     = WQ + 1572864;
  __hip_bfloat16* WP     = WO + 524288;
  __hip_bfloat16* KmemG  = WP + 262144;
  __hip_bfloat16* VmemTG = KmemG + 4096;

  wnorm_pack<<<3072, 64, 0, stream>>>(wqkv,  WQ);
  wnorm_pack<<<1024, 64, 0, stream>>>(wout,  WO);
  wnorm_pack<<<512,  64, 0, stream>>>(wproj, WP);
  memnorm<<<128, 64, 0, stream>>>(mkv, KmemG, VmemTG);

  transpose_in<<<dim3(32, 16, 32), dim3(32, 8), 0, stream>>>(x, Y0);

  const int M = 32768, NCH = M / CH;
  for (int layer = 0; layer < 2; ++layer) {
    const __hip_bfloat16* WQl = WQ + (size_t)layer * 786432;
    const __hip_bfloat16* WOl = WO + (size_t)layer * 262144;
    __hip_bfloat16* Acur = (layer == 0) ? Y0 : Ycur;
    for (int ch = 0; ch < NCH; ++ch) {
      const size_t m0 = (size_t)ch * CH;
      gemm3<0><<<dim3(12, CH / 128), 256, 0, stream>>>(Acur + m0 * 512, WQl, 512,
                                                       QKVc, 1536, nullptr, nullptr);
      attn_kernel<<<CH / 16, 256, 0, stream>>>(QKVc, KmemG + (size_t)layer * 2048,
                                               VmemTG + (size_t)layer * 2048);
      gemm3<1><<<dim3(4, CH / 128), 256, 0, stream>>>(QKVc, WOl, 1536,
                                                      Ycur + m0 * 512, 512,
                                                      Acur + m0 * 512, nullptr);
    }
  }

  gemm3<2><<<dim3(4, 256), 256, 0, stream>>>(Ycur, WP, 512, Y0, 512, Y0, gain);
  transpose_out<<<dim3(32, 16, 32), dim3(32, 8), 0, stream>>>(Y0, out);
}